// Round 9
// baseline (666.498 us; speedup 1.0000x reference)
//
#include <hip/hip_runtime.h>
#include <math.h>

#define WIDTH 256
#define PTS 16
#define NROW 80            // 5 chains * 16 points
#define CPLANE 20480       // halves per Z plane: 5v * 8kc * 64lane * 8

typedef _Float16 f16x8 __attribute__((ext_vector_type(8)));
typedef _Float16 f16x4 __attribute__((ext_vector_type(4)));
typedef __fp16   h16x2 __attribute__((ext_vector_type(2)));   // cvt_pkrtz return type
typedef float    f32x4 __attribute__((ext_vector_type(4)));

// fp32 -> fp16 hi + fp16 lo (2-split) -- used for WEIGHTS only (static, exact)
__device__ __forceinline__ void split2(float f, _Float16& h, _Float16& l) {
    h = (_Float16)f;
    l = (_Float16)(f - (float)h);
}
// z=tanh(u), s=1-z^2 = 4t/(1+t)^2 with t=exp(-2|u|): no cancellation in saturation.
// rcp via v_rcp_f32 (~1 ulp); verified absmax-neutral (r2/r6).
__device__ __forceinline__ void tanh_s(float u, float& z, float& s) {
    const float t = __expf(-2.0f * fabsf(u));
    const float r = __builtin_amdgcn_rcpf(1.0f + t);
    const float zm = (1.0f - t) * r;
    z = copysignf(zm, u);
    s = 4.0f * t * r * r;
}

// Pre-split w1..w5 into fp16 hi/lo, transposed + packed in MFMA A-frag order:
// wt2[(l*2+c)*65536 + ((jt*8+kc)*64 + lane)*8 + i] = comp_c(W[k][j]),
// j = jt*16 + (lane&15), k = kc*32 + (lane>>4)*8 + i.   (16x16x32 frag order)
__global__ void prep_w_kernel(const float* __restrict__ w1, const float* __restrict__ w2,
                              const float* __restrict__ w3, const float* __restrict__ w4,
                              const float* __restrict__ w5, _Float16* __restrict__ wt2)
{
    const int idx = blockIdx.x * blockDim.x + threadIdx.x;
    if (idx >= 5 * 16 * 8 * 64) return;
    const int lane = idx & 63;
    const int kc   = (idx >> 6) & 7;
    const int jt   = (idx >> 9) & 15;
    const int l    = idx >> 13;
    const float* Wsrc[5] = { w1, w2, w3, w4, w5 };
    const float* W = Wsrc[l];
    const int j  = jt * 16 + (lane & 15);
    const int k0 = kc * 32 + (lane >> 4) * 8;
    f16x8 vh, vl;
    #pragma unroll
    for (int i = 0; i < 8; ++i) {
        _Float16 h, lo;
        split2(W[(k0 + i) * WIDTH + j], h, lo);
        vh[i] = h; vl[i] = lo;
    }
    const int fo = ((jt * 8 + kc) * 64 + lane) * 8;
    *(f16x8*)(wt2 + (l * 2 + 0) * 65536 + fo) = vh;
    *(f16x8*)(wt2 + (l * 2 + 1) * 65536 + fo) = vl;
}

// r8 structure (2-3 blocks/CU) + pseudo-random start-phase stagger: co-resident
// blocks otherwise phase-lock (all-KL then all-EP; MfmaUtil+VALUBusy = 89% < 100,
// i.e. zero cross-pipe co-issue). A 0..3 quarter-phase s_sleep stagger seeds
// anti-phase so one block's MFMA k-loop co-issues with another's VALU epilogue
// (m114 regime). Numerics identical to r8.
__global__ __launch_bounds__(256, 2)
void pde_mfma_kernel(const float* __restrict__ xyt,
                     const float* __restrict__ w0, const float* __restrict__ b0,
                     const float* __restrict__ b1, const float* __restrict__ b2,
                     const float* __restrict__ b3, const float* __restrict__ b4,
                     const float* __restrict__ b5,
                     const float* __restrict__ w6, const float* __restrict__ b6,
                     const _Float16* __restrict__ wt2,
                     float* __restrict__ out)
{
    // Zs[((v*8 + kc)*64 + lane)*8 + i] = Z[point n = lane&15, k = kc*32 + (lane>>4)*8 + i]
    __shared__ _Float16 Zs[CPLANE];   // 40960 B
    float* redf = (float*)Zs;         // aliased reduction scratch (after last Z read)

    const int tid = threadIdx.x;
    const long gp0 = (long)blockIdx.x * PTS;

    // ---------------- start-phase stagger (uniform across block) ------------
    // hash(blockIdx) -> 0..3 units; each unit ~ s_sleep(7) x 7 ~ 3k cycles
    // ~ quarter of a KL phase. Mean cost ~1.5 us/block, amortized ~0 over the
    // 32 sequential block-passes per CU; breaks the t=0 cohort phase lock.
    {
        const unsigned db = (blockIdx.x * 2654435761u) >> 30;   // 0..3
        for (unsigned i = 0; i < db * 7u; ++i)
            __builtin_amdgcn_s_sleep(7);
    }

    // ---------------- layer 0: (3 -> 256), Taylor-mode, fp32 VALU ----------
    {
        const int p = tid & 15;
        const float x = xyt[(gp0 + p) * 3 + 0];
        const float y = xyt[(gp0 + p) * 3 + 1];
        const float t = xyt[(gp0 + p) * 3 + 2];
        #pragma unroll
        for (int half = 0; half < 2; ++half) {
            const int jg = (tid >> 4) + half * 16;   // 0..31, 8 features each
            f16x8 vh[5];
            #pragma unroll
            for (int c = 0; c < 8; ++c) {
                const int j = jg * 8 + c;
                const float wx = w0[0 * WIDTH + j];
                const float wy = w0[1 * WIDTH + j];
                const float wt = w0[2 * WIDTH + j];
                float zv, s;
                tanh_s(fmaf(x, wx, fmaf(y, wy, fmaf(t, wt, b0[j]))), zv, s);
                const float vals[5] = { zv, s * wx, s * wy, s * wt,
                                        -2.0f * zv * s * (wx * wx + wy * wy) };
                #pragma unroll
                for (int v = 0; v < 5; ++v)
                    vh[v][c] = (_Float16)vals[v];
            }
            // j block jg*8..+7: kc = jg>>2, q' = jg&3, i = c
            #pragma unroll
            for (int v = 0; v < 5; ++v) {
                const int off = ((v * 8 + (jg >> 2)) * 64 + (jg & 3) * 16 + p) * 8;
                *(f16x8*)&Zs[off] = vh[v];
            }
        }
    }
    __syncthreads();

    // ------- hidden layers 1..5: MFMA fp16; v=0: 2 products, v>=1: 1 -------
    const float* Bsl[5] = { b1, b2, b3, b4, b5 };
    const int lane = tid & 63;
    const int wv   = tid >> 6;       // wave 0..3 -> M-tiles 4w..4w+3
    const int q    = lane >> 4;
    const int n15  = lane & 15;

    for (int l = 0; l < 5; ++l) {
        const _Float16* Wl = wt2 + l * 2 * 65536;
        f32x4 acc[5][4];
        #pragma unroll
        for (int v = 0; v < 5; ++v)
            #pragma unroll
            for (int Mt = 0; Mt < 4; ++Mt)
                acc[v][Mt] = (f32x4){0.f, 0.f, 0.f, 0.f};

        #pragma unroll 2
        for (int kc = 0; kc < 8; ++kc) {
            f16x8 Ah[4], Al[4];
            #pragma unroll
            for (int Mt = 0; Mt < 4; ++Mt) {
                const int fo = (((wv * 4 + Mt) * 8 + kc) * 64 + lane) * 8;
                Ah[Mt] = *(const f16x8*)(Wl + fo);
                Al[Mt] = *(const f16x8*)(Wl + 65536 + fo);
            }
            #pragma unroll
            for (int v = 0; v < 5; ++v) {
                const int zo = ((v * 8 + kc) * 64 + lane) * 8;
                const f16x8 Bh = *(const f16x8*)&Zs[zo];
                #pragma unroll
                for (int Mt = 0; Mt < 4; ++Mt) {
                    f32x4 a = acc[v][Mt];
                    if (v == 0)   // value chain: weight-lo correction kept
                        a = __builtin_amdgcn_mfma_f32_16x16x32_f16(Al[Mt], Bh, a, 0, 0, 0);
                    a = __builtin_amdgcn_mfma_f32_16x16x32_f16(Ah[Mt], Bh, a, 0, 0, 0);
                    acc[v][Mt] = a;
                }
            }
        }
        __syncthreads();   // all Zs reads done before overwrite

        // epilogue: lane holds (j = jt*16 + q*4 + reg, p = n15), all 5 chains
        const float* Bb = Bsl[l];
        #pragma unroll
        for (int Mt = 0; Mt < 4; ++Mt) {
            const int jt = wv * 4 + Mt;
            float nv[5][4];
            #pragma unroll
            for (int reg = 0; reg < 4; ++reg) {
                const int j = jt * 16 + q * 4 + reg;
                float zv, s;
                tanh_s(acc[0][Mt][reg] + Bb[j], zv, s);
                const float u1 = acc[1][Mt][reg];
                const float u2 = acc[2][Mt][reg];
                nv[0][reg] = zv;
                nv[1][reg] = s * u1;
                nv[2][reg] = s * u2;
                nv[3][reg] = s * acc[3][Mt][reg];
                nv[4][reg] = fmaf(-2.0f * zv * s, fmaf(u1, u1, u2 * u2),
                                  s * acc[4][Mt][reg]);
            }
            // j0 = jt*16 + q*4 -> kc' = j0>>5, q'' = (j0>>3)&3, i0 = j0&7
            const int j0 = jt * 16 + q * 4;
            const int off0 = ((j0 >> 5) * 64 + ((j0 >> 3) & 3) * 16 + n15) * 8 + (j0 & 7);
            #pragma unroll
            for (int v = 0; v < 5; ++v) {
                const h16x2 h01 = __builtin_amdgcn_cvt_pkrtz(nv[v][0], nv[v][1]);
                const h16x2 h23 = __builtin_amdgcn_cvt_pkrtz(nv[v][2], nv[v][3]);
                *(f16x4*)&Zs[v * 4096 + off0] =
                    (f16x4){ (_Float16)h01[0], (_Float16)h01[1],
                             (_Float16)h23[0], (_Float16)h23[1] };
            }
        }
        __syncthreads();
    }

    // ---------------- final layer: (256 -> 1) dot products ------------------
    // 80 rows x 2 halves of 128 features; 160 active threads.
    float partial = 0.f;
    const int n    = tid >> 1;        // row 0..79 (valid if tid < 160)
    const int half = tid & 1;
    if (tid < 2 * NROW) {
        const int v = n >> 4, p = n & 15;
        for (int kk = half * 128; kk < half * 128 + 128; kk += 8) {
            const int off = ((v * 8 + (kk >> 5)) * 64 + ((kk >> 3) & 3) * 16 + p) * 8;
            const f16x8 zh = *(const f16x8*)&Zs[off];
            #pragma unroll
            for (int i = 0; i < 8; ++i)
                partial = fmaf((float)zh[i], w6[kk + i], partial);
        }
    }
    __syncthreads();                 // all reads of Zs done before aliasing
    if (tid < 2 * NROW) redf[half * NROW + n] = partial;
    __syncthreads();
    if (tid < NROW) redf[2 * NROW + tid] = redf[tid] + redf[NROW + tid];
    __syncthreads();

    // ---------------- residual ----------------
    if (tid < PTS) {
        const int p = tid;
        const float* tot = redf + 2 * NROW;
        const float h   = tot[0 * 16 + p] + b6[0];
        const float hx  = tot[1 * 16 + p];
        const float hy  = tot[2 * 16 + p];
        const float ht  = tot[3 * 16 + p];
        const float lap = tot[4 * 16 + p];
        const float x = xyt[(gp0 + p) * 3 + 0];
        const float y = xyt[(gp0 + p) * 3 + 1];
        const float t = xyt[(gp0 + p) * 3 + 2];
        const float pi = 3.14159265358979323846f;
        const float f = sinf(pi * x) * sinf(pi * y) * expf(-t);
        out[gp0 + p] = ht - 0.5f * (fmaf(h, lap, fmaf(hx, hx, hy * hy))) - f;
    }
}

extern "C" void kernel_launch(void* const* d_in, const int* in_sizes, int n_in,
                              void* d_out, int out_size, void* d_ws, size_t ws_size,
                              hipStream_t stream) {
    const float* xyt = (const float*)d_in[0];
    const float* w0  = (const float*)d_in[1];
    const float* b0  = (const float*)d_in[2];
    const float* w1  = (const float*)d_in[3];
    const float* b1  = (const float*)d_in[4];
    const float* w2  = (const float*)d_in[5];
    const float* b2  = (const float*)d_in[6];
    const float* w3  = (const float*)d_in[7];
    const float* b3  = (const float*)d_in[8];
    const float* w4  = (const float*)d_in[9];
    const float* b4  = (const float*)d_in[10];
    const float* w5  = (const float*)d_in[11];
    const float* b5  = (const float*)d_in[12];
    const float* w6  = (const float*)d_in[13];
    const float* b6  = (const float*)d_in[14];
    float* out = (float*)d_out;
    _Float16* wt2 = (_Float16*)d_ws;    // needs 5*2*65536*2 = 1,310,720 B

    prep_w_kernel<<<160, 256, 0, stream>>>(w1, w2, w3, w4, w5, wt2);

    const int npts = in_sizes[0] / 3;   // 131072
    dim3 grid(npts / PTS);              // 8192
    dim3 block(256);
    pde_mfma_kernel<<<grid, block, 0, stream>>>(xyt, w0, b0, b1, b2, b3, b4, b5,
                                                w6, b6, wt2, out);
}

// Round 10
// 627.036 us; speedup vs baseline: 1.0629x; 1.0629x over previous
//
#include <hip/hip_runtime.h>
#include <math.h>

#define WIDTH 256
#define PTS 16
#define CPLANE 20480       // halves per Z plane: 5v * 8kc * 64lane * 8

typedef _Float16 f16x8 __attribute__((ext_vector_type(8)));
typedef _Float16 f16x4 __attribute__((ext_vector_type(4)));
typedef __fp16   h16x2 __attribute__((ext_vector_type(2)));   // cvt_pkrtz return type
typedef float    f32x4 __attribute__((ext_vector_type(4)));

// fp32 -> fp16 hi + fp16 lo (2-split) -- used for WEIGHTS only (static, exact)
__device__ __forceinline__ void split2(float f, _Float16& h, _Float16& l) {
    h = (_Float16)f;
    l = (_Float16)(f - (float)h);
}
// z=tanh(u), s=1-z^2 = 4t/(1+t)^2 with t=exp(-2|u|): no cancellation in saturation.
// rcp via v_rcp_f32 (~1 ulp); verified absmax-neutral (r2/r6).
__device__ __forceinline__ void tanh_s(float u, float& z, float& s) {
    const float t = __expf(-2.0f * fabsf(u));
    const float r = __builtin_amdgcn_rcpf(1.0f + t);
    const float zm = (1.0f - t) * r;
    z = copysignf(zm, u);
    s = 4.0f * t * r * r;
}

// Pre-split w1..w5 into fp16 hi/lo, transposed + packed in MFMA A-frag order:
// wt2[(l*2+c)*65536 + ((jt*8+kc)*64 + lane)*8 + i] = comp_c(W[k][j]),
// j = jt*16 + (lane&15), k = kc*32 + (lane>>4)*8 + i.   (16x16x32 frag order)
__global__ void prep_w_kernel(const float* __restrict__ w1, const float* __restrict__ w2,
                              const float* __restrict__ w3, const float* __restrict__ w4,
                              const float* __restrict__ w5, _Float16* __restrict__ wt2)
{
    const int idx = blockIdx.x * blockDim.x + threadIdx.x;
    if (idx >= 5 * 16 * 8 * 64) return;
    const int lane = idx & 63;
    const int kc   = (idx >> 6) & 7;
    const int jt   = (idx >> 9) & 15;
    const int l    = idx >> 13;
    const float* Wsrc[5] = { w1, w2, w3, w4, w5 };
    const float* W = Wsrc[l];
    const int j  = jt * 16 + (lane & 15);
    const int k0 = kc * 32 + (lane >> 4) * 8;
    f16x8 vh, vl;
    #pragma unroll
    for (int i = 0; i < 8; ++i) {
        _Float16 h, lo;
        split2(W[(k0 + i) * WIDTH + j], h, lo);
        vh[i] = h; vl[i] = lo;
    }
    const int fo = ((jt * 8 + kc) * 64 + lane) * 8;
    *(f16x8*)(wt2 + (l * 2 + 0) * 65536 + fo) = vh;
    *(f16x8*)(wt2 + (l * 2 + 1) * 65536 + fo) = vl;
}

// r8 structure (2-3 blocks/CU, serial phases; overlap attempts closed after 5
// failures). New here: the final (256->1) layer is FOLDED into layer-5's
// epilogue -- each thread dots its 16 in-register nv features with w6 and the
// 16 threads per point reduce via shfl_xor + one small LDS buffer. Deletes the
// FDOT phase, layer-5 Z packing/stores, one reduction stage, and 2 barriers;
// final dot uses unquantized f32 values (accuracy same or better).
__global__ __launch_bounds__(256, 2)
void pde_mfma_kernel(const float* __restrict__ xyt,
                     const float* __restrict__ w0, const float* __restrict__ b0,
                     const float* __restrict__ b1, const float* __restrict__ b2,
                     const float* __restrict__ b3, const float* __restrict__ b4,
                     const float* __restrict__ b5,
                     const float* __restrict__ w6, const float* __restrict__ b6,
                     const _Float16* __restrict__ wt2,
                     float* __restrict__ out)
{
    // Zs[((v*8 + kc)*64 + lane)*8 + i] = Z[point n = lane&15, k = kc*32 + (lane>>4)*8 + i]
    __shared__ _Float16 Zs[CPLANE];   // 40960 B
    float* redf = (float*)Zs;         // aliased reduction scratch (after last Z read)

    const int tid = threadIdx.x;
    const long gp0 = (long)blockIdx.x * PTS;

    // ---------------- layer 0: (3 -> 256), Taylor-mode, fp32 VALU ----------
    {
        const int p = tid & 15;
        const float x = xyt[(gp0 + p) * 3 + 0];
        const float y = xyt[(gp0 + p) * 3 + 1];
        const float t = xyt[(gp0 + p) * 3 + 2];
        #pragma unroll
        for (int half = 0; half < 2; ++half) {
            const int jg = (tid >> 4) + half * 16;   // 0..31, 8 features each
            f16x8 vh[5];
            #pragma unroll
            for (int c = 0; c < 8; ++c) {
                const int j = jg * 8 + c;
                const float wx = w0[0 * WIDTH + j];
                const float wy = w0[1 * WIDTH + j];
                const float wt = w0[2 * WIDTH + j];
                float zv, s;
                tanh_s(fmaf(x, wx, fmaf(y, wy, fmaf(t, wt, b0[j]))), zv, s);
                const float vals[5] = { zv, s * wx, s * wy, s * wt,
                                        -2.0f * zv * s * (wx * wx + wy * wy) };
                #pragma unroll
                for (int v = 0; v < 5; ++v)
                    vh[v][c] = (_Float16)vals[v];
            }
            // j block jg*8..+7: kc = jg>>2, q' = jg&3, i = c
            #pragma unroll
            for (int v = 0; v < 5; ++v) {
                const int off = ((v * 8 + (jg >> 2)) * 64 + (jg & 3) * 16 + p) * 8;
                *(f16x8*)&Zs[off] = vh[v];
            }
        }
    }
    __syncthreads();

    // ------- hidden layers 1..5: MFMA fp16; v=0: 2 products, v>=1: 1 -------
    const float* Bsl[5] = { b1, b2, b3, b4, b5 };
    const int lane = tid & 63;
    const int wv   = tid >> 6;       // wave 0..3 -> M-tiles 4w..4w+3
    const int q    = lane >> 4;
    const int n15  = lane & 15;

    for (int l = 0; l < 5; ++l) {
        const _Float16* Wl = wt2 + l * 2 * 65536;
        f32x4 acc[5][4];
        #pragma unroll
        for (int v = 0; v < 5; ++v)
            #pragma unroll
            for (int Mt = 0; Mt < 4; ++Mt)
                acc[v][Mt] = (f32x4){0.f, 0.f, 0.f, 0.f};

        #pragma unroll 2
        for (int kc = 0; kc < 8; ++kc) {
            f16x8 Ah[4], Al[4];
            #pragma unroll
            for (int Mt = 0; Mt < 4; ++Mt) {
                const int fo = (((wv * 4 + Mt) * 8 + kc) * 64 + lane) * 8;
                Ah[Mt] = *(const f16x8*)(Wl + fo);
                Al[Mt] = *(const f16x8*)(Wl + 65536 + fo);
            }
            #pragma unroll
            for (int v = 0; v < 5; ++v) {
                const int zo = ((v * 8 + kc) * 64 + lane) * 8;
                const f16x8 Bh = *(const f16x8*)&Zs[zo];
                #pragma unroll
                for (int Mt = 0; Mt < 4; ++Mt) {
                    f32x4 a = acc[v][Mt];
                    if (v == 0)   // value chain: weight-lo correction kept
                        a = __builtin_amdgcn_mfma_f32_16x16x32_f16(Al[Mt], Bh, a, 0, 0, 0);
                    a = __builtin_amdgcn_mfma_f32_16x16x32_f16(Ah[Mt], Bh, a, 0, 0, 0);
                    acc[v][Mt] = a;
                }
            }
        }
        __syncthreads();   // all Zs reads done before overwrite / redf alias

        const float* Bb = Bsl[l];
        if (l < 4) {
            // epilogue -> next-layer Z (fp16 hi), store to Zs
            #pragma unroll
            for (int Mt = 0; Mt < 4; ++Mt) {
                const int jt = wv * 4 + Mt;
                float nv[5][4];
                #pragma unroll
                for (int reg = 0; reg < 4; ++reg) {
                    const int j = jt * 16 + q * 4 + reg;
                    float zv, s;
                    tanh_s(acc[0][Mt][reg] + Bb[j], zv, s);
                    const float u1 = acc[1][Mt][reg];
                    const float u2 = acc[2][Mt][reg];
                    nv[0][reg] = zv;
                    nv[1][reg] = s * u1;
                    nv[2][reg] = s * u2;
                    nv[3][reg] = s * acc[3][Mt][reg];
                    nv[4][reg] = fmaf(-2.0f * zv * s, fmaf(u1, u1, u2 * u2),
                                      s * acc[4][Mt][reg]);
                }
                const int j0 = jt * 16 + q * 4;
                const int off0 = ((j0 >> 5) * 64 + ((j0 >> 3) & 3) * 16 + n15) * 8 + (j0 & 7);
                #pragma unroll
                for (int v = 0; v < 5; ++v) {
                    const h16x2 h01 = __builtin_amdgcn_cvt_pkrtz(nv[v][0], nv[v][1]);
                    const h16x2 h23 = __builtin_amdgcn_cvt_pkrtz(nv[v][2], nv[v][3]);
                    *(f16x4*)&Zs[v * 4096 + off0] =
                        (f16x4){ (_Float16)h01[0], (_Float16)h01[1],
                                 (_Float16)h23[0], (_Float16)h23[1] };
                }
            }
        } else {
            // final epilogue: tanh chain + fold w6 dot, all in f32 registers.
            float part[5] = {0.f, 0.f, 0.f, 0.f, 0.f};
            #pragma unroll
            for (int Mt = 0; Mt < 4; ++Mt) {
                const int jt = wv * 4 + Mt;
                #pragma unroll
                for (int reg = 0; reg < 4; ++reg) {
                    const int j = jt * 16 + q * 4 + reg;
                    float zv, s;
                    tanh_s(acc[0][Mt][reg] + Bb[j], zv, s);
                    const float u1 = acc[1][Mt][reg];
                    const float u2 = acc[2][Mt][reg];
                    const float w6j = w6[j];
                    part[0] = fmaf(zv, w6j, part[0]);
                    part[1] = fmaf(s * u1, w6j, part[1]);
                    part[2] = fmaf(s * u2, w6j, part[2]);
                    part[3] = fmaf(s * acc[3][Mt][reg], w6j, part[3]);
                    part[4] = fmaf(fmaf(-2.0f * zv * s, fmaf(u1, u1, u2 * u2),
                                        s * acc[4][Mt][reg]), w6j, part[4]);
                }
            }
            // reduce over q (lanes n15, n15+16, n15+32, n15+48) via shfl_xor
            #pragma unroll
            for (int v = 0; v < 5; ++v) {
                part[v] += __shfl_xor(part[v], 16, 64);
                part[v] += __shfl_xor(part[v], 32, 64);
            }
            // per-wave partials -> LDS (redf aliases Zs; all Zs reads barrier'd)
            if (q == 0) {
                #pragma unroll
                for (int v = 0; v < 5; ++v)
                    redf[wv * 80 + v * 16 + n15] = part[v];
            }
        }
        __syncthreads();
    }

    // ---------------- residual (sum 4 wave partials per chain) --------------
    if (tid < PTS) {
        const int p = tid;
        float tot[5];
        #pragma unroll
        for (int v = 0; v < 5; ++v)
            tot[v] = redf[0 * 80 + v * 16 + p] + redf[1 * 80 + v * 16 + p]
                   + redf[2 * 80 + v * 16 + p] + redf[3 * 80 + v * 16 + p];
        const float h   = tot[0] + b6[0];
        const float hx  = tot[1];
        const float hy  = tot[2];
        const float ht  = tot[3];
        const float lap = tot[4];
        const float x = xyt[(gp0 + p) * 3 + 0];
        const float y = xyt[(gp0 + p) * 3 + 1];
        const float t = xyt[(gp0 + p) * 3 + 2];
        const float pi = 3.14159265358979323846f;
        const float f = sinf(pi * x) * sinf(pi * y) * expf(-t);
        out[gp0 + p] = ht - 0.5f * (fmaf(h, lap, fmaf(hx, hx, hy * hy))) - f;
    }
}

extern "C" void kernel_launch(void* const* d_in, const int* in_sizes, int n_in,
                              void* d_out, int out_size, void* d_ws, size_t ws_size,
                              hipStream_t stream) {
    const float* xyt = (const float*)d_in[0];
    const float* w0  = (const float*)d_in[1];
    const float* b0  = (const float*)d_in[2];
    const float* w1  = (const float*)d_in[3];
    const float* b1  = (const float*)d_in[4];
    const float* w2  = (const float*)d_in[5];
    const float* b2  = (const float*)d_in[6];
    const float* w3  = (const float*)d_in[7];
    const float* b3  = (const float*)d_in[8];
    const float* w4  = (const float*)d_in[9];
    const float* b4  = (const float*)d_in[10];
    const float* w5  = (const float*)d_in[11];
    const float* b5  = (const float*)d_in[12];
    const float* w6  = (const float*)d_in[13];
    const float* b6  = (const float*)d_in[14];
    float* out = (float*)d_out;
    _Float16* wt2 = (_Float16*)d_ws;    // needs 5*2*65536*2 = 1,310,720 B

    prep_w_kernel<<<160, 256, 0, stream>>>(w1, w2, w3, w4, w5, wt2);

    const int npts = in_sizes[0] / 3;   // 131072
    dim3 grid(npts / PTS);              // 8192
    dim3 block(256);
    pde_mfma_kernel<<<grid, block, 0, stream>>>(xyt, w0, b0, b1, b2, b3, b4, b5,
                                                w6, b6, wt2, out);
}

// Round 11
// 503.281 us; speedup vs baseline: 1.3243x; 1.2459x over previous
//
#include <hip/hip_runtime.h>
#include <math.h>

#define WIDTH 256
#define PTS 16
#define CPLANE 20480       // halves per Z plane: 5v * 8kc * 64lane * 8

typedef _Float16 f16x8 __attribute__((ext_vector_type(8)));
typedef _Float16 f16x4 __attribute__((ext_vector_type(4)));
typedef __fp16   h16x2 __attribute__((ext_vector_type(2)));   // cvt_pkrtz return type
typedef float    f32x4 __attribute__((ext_vector_type(4)));

// fp32 -> fp16 hi + fp16 lo (2-split). The lo plane is still written by prep
// (layout kept stable) but no longer read by the main kernel.
__device__ __forceinline__ void split2(float f, _Float16& h, _Float16& l) {
    h = (_Float16)f;
    l = (_Float16)(f - (float)h);
}
// z=tanh(u), s=1-z^2 = 4t/(1+t)^2 with t=exp(-2|u|): no cancellation in saturation.
// rcp via v_rcp_f32 (~1 ulp); verified absmax-neutral (r2/r6).
__device__ __forceinline__ void tanh_s(float u, float& z, float& s) {
    const float t = __expf(-2.0f * fabsf(u));
    const float r = __builtin_amdgcn_rcpf(1.0f + t);
    const float zm = (1.0f - t) * r;
    z = copysignf(zm, u);
    s = 4.0f * t * r * r;
}

// Pre-split w1..w5 into fp16 hi/lo, transposed + packed in MFMA A-frag order:
// wt2[(l*2+c)*65536 + ((jt*8+kc)*64 + lane)*8 + i] = comp_c(W[k][j]),
// j = jt*16 + (lane&15), k = kc*32 + (lane>>4)*8 + i.   (16x16x32 frag order)
__global__ void prep_w_kernel(const float* __restrict__ w1, const float* __restrict__ w2,
                              const float* __restrict__ w3, const float* __restrict__ w4,
                              const float* __restrict__ w5, _Float16* __restrict__ wt2)
{
    const int idx = blockIdx.x * blockDim.x + threadIdx.x;
    if (idx >= 5 * 16 * 8 * 64) return;
    const int lane = idx & 63;
    const int kc   = (idx >> 6) & 7;
    const int jt   = (idx >> 9) & 15;
    const int l    = idx >> 13;
    const float* Wsrc[5] = { w1, w2, w3, w4, w5 };
    const float* W = Wsrc[l];
    const int j  = jt * 16 + (lane & 15);
    const int k0 = kc * 32 + (lane >> 4) * 8;
    f16x8 vh, vl;
    #pragma unroll
    for (int i = 0; i < 8; ++i) {
        _Float16 h, lo;
        split2(W[(k0 + i) * WIDTH + j], h, lo);
        vh[i] = h; vl[i] = lo;
    }
    const int fo = ((jt * 8 + kc) * 64 + lane) * 8;
    *(f16x8*)(wt2 + (l * 2 + 0) * 65536 + fo) = vh;
    *(f16x8*)(wt2 + (l * 2 + 1) * 65536 + fo) = vl;
}

// r10 structure with the last redundant MFMA product removed: ALL chains now
// single-product Ah*Bh (pure fp16-hi weights). MFMA floor 249 -> 208 us, and
// the dead Al weight stream (4 global b128/kc) is deleted. Evidence for the
// numeric gamble: r6's identical cut on the 4 derivative chains left absmax
// pinned at exactly 2^-8 through every round since.
__global__ __launch_bounds__(256, 2)
void pde_mfma_kernel(const float* __restrict__ xyt,
                     const float* __restrict__ w0, const float* __restrict__ b0,
                     const float* __restrict__ b1, const float* __restrict__ b2,
                     const float* __restrict__ b3, const float* __restrict__ b4,
                     const float* __restrict__ b5,
                     const float* __restrict__ w6, const float* __restrict__ b6,
                     const _Float16* __restrict__ wt2,
                     float* __restrict__ out)
{
    // Zs[((v*8 + kc)*64 + lane)*8 + i] = Z[point n = lane&15, k = kc*32 + (lane>>4)*8 + i]
    __shared__ _Float16 Zs[CPLANE];   // 40960 B
    float* redf = (float*)Zs;         // aliased reduction scratch (after last Z read)

    const int tid = threadIdx.x;
    const long gp0 = (long)blockIdx.x * PTS;

    // ---------------- layer 0: (3 -> 256), Taylor-mode, fp32 VALU ----------
    {
        const int p = tid & 15;
        const float x = xyt[(gp0 + p) * 3 + 0];
        const float y = xyt[(gp0 + p) * 3 + 1];
        const float t = xyt[(gp0 + p) * 3 + 2];
        #pragma unroll
        for (int half = 0; half < 2; ++half) {
            const int jg = (tid >> 4) + half * 16;   // 0..31, 8 features each
            f16x8 vh[5];
            #pragma unroll
            for (int c = 0; c < 8; ++c) {
                const int j = jg * 8 + c;
                const float wx = w0[0 * WIDTH + j];
                const float wy = w0[1 * WIDTH + j];
                const float wt = w0[2 * WIDTH + j];
                float zv, s;
                tanh_s(fmaf(x, wx, fmaf(y, wy, fmaf(t, wt, b0[j]))), zv, s);
                const float vals[5] = { zv, s * wx, s * wy, s * wt,
                                        -2.0f * zv * s * (wx * wx + wy * wy) };
                #pragma unroll
                for (int v = 0; v < 5; ++v)
                    vh[v][c] = (_Float16)vals[v];
            }
            // j block jg*8..+7: kc = jg>>2, q' = jg&3, i = c
            #pragma unroll
            for (int v = 0; v < 5; ++v) {
                const int off = ((v * 8 + (jg >> 2)) * 64 + (jg & 3) * 16 + p) * 8;
                *(f16x8*)&Zs[off] = vh[v];
            }
        }
    }
    __syncthreads();

    // ------- hidden layers 1..5: MFMA fp16, single product per chain -------
    const float* Bsl[5] = { b1, b2, b3, b4, b5 };
    const int lane = tid & 63;
    const int wv   = tid >> 6;       // wave 0..3 -> M-tiles 4w..4w+3
    const int q    = lane >> 4;
    const int n15  = lane & 15;

    for (int l = 0; l < 5; ++l) {
        const _Float16* Wl = wt2 + l * 2 * 65536;
        f32x4 acc[5][4];
        #pragma unroll
        for (int v = 0; v < 5; ++v)
            #pragma unroll
            for (int Mt = 0; Mt < 4; ++Mt)
                acc[v][Mt] = (f32x4){0.f, 0.f, 0.f, 0.f};

        #pragma unroll 2
        for (int kc = 0; kc < 8; ++kc) {
            f16x8 Ah[4];
            #pragma unroll
            for (int Mt = 0; Mt < 4; ++Mt) {
                const int fo = (((wv * 4 + Mt) * 8 + kc) * 64 + lane) * 8;
                Ah[Mt] = *(const f16x8*)(Wl + fo);
            }
            #pragma unroll
            for (int v = 0; v < 5; ++v) {
                const int zo = ((v * 8 + kc) * 64 + lane) * 8;
                const f16x8 Bh = *(const f16x8*)&Zs[zo];
                #pragma unroll
                for (int Mt = 0; Mt < 4; ++Mt)
                    acc[v][Mt] = __builtin_amdgcn_mfma_f32_16x16x32_f16(
                                     Ah[Mt], Bh, acc[v][Mt], 0, 0, 0);
            }
        }
        __syncthreads();   // all Zs reads done before overwrite / redf alias

        const float* Bb = Bsl[l];
        if (l < 4) {
            // epilogue -> next-layer Z (fp16 hi), store to Zs
            #pragma unroll
            for (int Mt = 0; Mt < 4; ++Mt) {
                const int jt = wv * 4 + Mt;
                float nv[5][4];
                #pragma unroll
                for (int reg = 0; reg < 4; ++reg) {
                    const int j = jt * 16 + q * 4 + reg;
                    float zv, s;
                    tanh_s(acc[0][Mt][reg] + Bb[j], zv, s);
                    const float u1 = acc[1][Mt][reg];
                    const float u2 = acc[2][Mt][reg];
                    nv[0][reg] = zv;
                    nv[1][reg] = s * u1;
                    nv[2][reg] = s * u2;
                    nv[3][reg] = s * acc[3][Mt][reg];
                    nv[4][reg] = fmaf(-2.0f * zv * s, fmaf(u1, u1, u2 * u2),
                                      s * acc[4][Mt][reg]);
                }
                const int j0 = jt * 16 + q * 4;
                const int off0 = ((j0 >> 5) * 64 + ((j0 >> 3) & 3) * 16 + n15) * 8 + (j0 & 7);
                #pragma unroll
                for (int v = 0; v < 5; ++v) {
                    const h16x2 h01 = __builtin_amdgcn_cvt_pkrtz(nv[v][0], nv[v][1]);
                    const h16x2 h23 = __builtin_amdgcn_cvt_pkrtz(nv[v][2], nv[v][3]);
                    *(f16x4*)&Zs[v * 4096 + off0] =
                        (f16x4){ (_Float16)h01[0], (_Float16)h01[1],
                                 (_Float16)h23[0], (_Float16)h23[1] };
                }
            }
        } else {
            // final epilogue: tanh chain + fold w6 dot, all in f32 registers.
            float part[5] = {0.f, 0.f, 0.f, 0.f, 0.f};
            #pragma unroll
            for (int Mt = 0; Mt < 4; ++Mt) {
                const int jt = wv * 4 + Mt;
                #pragma unroll
                for (int reg = 0; reg < 4; ++reg) {
                    const int j = jt * 16 + q * 4 + reg;
                    float zv, s;
                    tanh_s(acc[0][Mt][reg] + Bb[j], zv, s);
                    const float u1 = acc[1][Mt][reg];
                    const float u2 = acc[2][Mt][reg];
                    const float w6j = w6[j];
                    part[0] = fmaf(zv, w6j, part[0]);
                    part[1] = fmaf(s * u1, w6j, part[1]);
                    part[2] = fmaf(s * u2, w6j, part[2]);
                    part[3] = fmaf(s * acc[3][Mt][reg], w6j, part[3]);
                    part[4] = fmaf(fmaf(-2.0f * zv * s, fmaf(u1, u1, u2 * u2),
                                        s * acc[4][Mt][reg]), w6j, part[4]);
                }
            }
            // reduce over q (lanes n15, n15+16, n15+32, n15+48) via shfl_xor
            #pragma unroll
            for (int v = 0; v < 5; ++v) {
                part[v] += __shfl_xor(part[v], 16, 64);
                part[v] += __shfl_xor(part[v], 32, 64);
            }
            // per-wave partials -> LDS (redf aliases Zs; all Zs reads barrier'd)
            if (q == 0) {
                #pragma unroll
                for (int v = 0; v < 5; ++v)
                    redf[wv * 80 + v * 16 + n15] = part[v];
            }
        }
        __syncthreads();
    }

    // ---------------- residual (sum 4 wave partials per chain) --------------
    if (tid < PTS) {
        const int p = tid;
        float tot[5];
        #pragma unroll
        for (int v = 0; v < 5; ++v)
            tot[v] = redf[0 * 80 + v * 16 + p] + redf[1 * 80 + v * 16 + p]
                   + redf[2 * 80 + v * 16 + p] + redf[3 * 80 + v * 16 + p];
        const float h   = tot[0] + b6[0];
        const float hx  = tot[1];
        const float hy  = tot[2];
        const float ht  = tot[3];
        const float lap = tot[4];
        const float x = xyt[(gp0 + p) * 3 + 0];
        const float y = xyt[(gp0 + p) * 3 + 1];
        const float t = xyt[(gp0 + p) * 3 + 2];
        const float pi = 3.14159265358979323846f;
        const float f = sinf(pi * x) * sinf(pi * y) * expf(-t);
        out[gp0 + p] = ht - 0.5f * (fmaf(h, lap, fmaf(hx, hx, hy * hy))) - f;
    }
}

extern "C" void kernel_launch(void* const* d_in, const int* in_sizes, int n_in,
                              void* d_out, int out_size, void* d_ws, size_t ws_size,
                              hipStream_t stream) {
    const float* xyt = (const float*)d_in[0];
    const float* w0  = (const float*)d_in[1];
    const float* b0  = (const float*)d_in[2];
    const float* w1  = (const float*)d_in[3];
    const float* b1  = (const float*)d_in[4];
    const float* w2  = (const float*)d_in[5];
    const float* b2  = (const float*)d_in[6];
    const float* w3  = (const float*)d_in[7];
    const float* b3  = (const float*)d_in[8];
    const float* w4  = (const float*)d_in[9];
    const float* b4  = (const float*)d_in[10];
    const float* w5  = (const float*)d_in[11];
    const float* b5  = (const float*)d_in[12];
    const float* w6  = (const float*)d_in[13];
    const float* b6  = (const float*)d_in[14];
    float* out = (float*)d_out;
    _Float16* wt2 = (_Float16*)d_ws;    // needs 5*2*65536*2 = 1,310,720 B

    prep_w_kernel<<<160, 256, 0, stream>>>(w1, w2, w3, w4, w5, wt2);

    const int npts = in_sizes[0] / 3;   // 131072
    dim3 grid(npts / PTS);              // 8192
    dim3 block(256);
    pde_mfma_kernel<<<grid, block, 0, stream>>>(xyt, w0, b0, b1, b2, b3, b4, b5,
                                                w6, b6, wt2, out);
}

// Round 12
// 498.664 us; speedup vs baseline: 1.3366x; 1.0093x over previous
//
#include <hip/hip_runtime.h>
#include <math.h>

#define WIDTH 256
#define PTS 16
#define CPLANE 20480       // halves per Z plane: 5v * 8kc * 64lane * 8

typedef _Float16 f16x8 __attribute__((ext_vector_type(8)));
typedef _Float16 f16x4 __attribute__((ext_vector_type(4)));
typedef __fp16   h16x2 __attribute__((ext_vector_type(2)));   // cvt_pkrtz return type
typedef float    f32x4 __attribute__((ext_vector_type(4)));

// fp32 -> fp16 hi + fp16 lo (2-split). The lo plane is still written by prep
// (layout kept stable) but no longer read by the main kernel.
__device__ __forceinline__ void split2(float f, _Float16& h, _Float16& l) {
    h = (_Float16)f;
    l = (_Float16)(f - (float)h);
}
// z=tanh(u), s=1-z^2 = 4t/(1+t)^2 with t=exp(-2u), u clamped to [-9,9]
// (clamp replaces fabs+copysign: exp stays in range both directions; at |u|=9
// z is saturated to ~1e-8 of +-1 and s ~ 6e-8 -- identical to the abs form).
__device__ __forceinline__ void tanh_s(float u, float& z, float& s) {
    const float uc = fminf(9.0f, fmaxf(-9.0f, u));
    const float t = __expf(-2.0f * uc);
    const float r = __builtin_amdgcn_rcpf(1.0f + t);
    z = (1.0f - t) * r;
    s = 4.0f * t * r * r;
}

// Pre-split w1..w5 into fp16 hi/lo, transposed + packed in MFMA A-frag order:
// wt2[(l*2+c)*65536 + ((jt*8+kc)*64 + lane)*8 + i] = comp_c(W[k][j]),
// j = jt*16 + (lane&15), k = kc*32 + (lane>>4)*8 + i.   (16x16x32 frag order)
__global__ void prep_w_kernel(const float* __restrict__ w1, const float* __restrict__ w2,
                              const float* __restrict__ w3, const float* __restrict__ w4,
                              const float* __restrict__ w5, _Float16* __restrict__ wt2)
{
    const int idx = blockIdx.x * blockDim.x + threadIdx.x;
    if (idx >= 5 * 16 * 8 * 64) return;
    const int lane = idx & 63;
    const int kc   = (idx >> 6) & 7;
    const int jt   = (idx >> 9) & 15;
    const int l    = idx >> 13;
    const float* Wsrc[5] = { w1, w2, w3, w4, w5 };
    const float* W = Wsrc[l];
    const int j  = jt * 16 + (lane & 15);
    const int k0 = kc * 32 + (lane >> 4) * 8;
    f16x8 vh, vl;
    #pragma unroll
    for (int i = 0; i < 8; ++i) {
        _Float16 h, lo;
        split2(W[(k0 + i) * WIDTH + j], h, lo);
        vh[i] = h; vl[i] = lo;
    }
    const int fo = ((jt * 8 + kc) * 64 + lane) * 8;
    *(f16x8*)(wt2 + (l * 2 + 0) * 65536 + fo) = vh;
    *(f16x8*)(wt2 + (l * 2 + 1) * 65536 + fo) = vl;
}

// r11 structure (single-product fp16-hi MFMA = 205 us floor; serial pipes)
// with the VALU term slimmed: float4 global loads (w0/b0/bias/w6), f32x4
// vector nv math (fma contraction + possible v_pk_f32 dual-issue), clamp-form
// tanh (no fabs/copysign), launch_bounds(256,4) residency/regalloc hint.
__global__ __launch_bounds__(256, 4)
void pde_mfma_kernel(const float* __restrict__ xyt,
                     const float* __restrict__ w0, const float* __restrict__ b0,
                     const float* __restrict__ b1, const float* __restrict__ b2,
                     const float* __restrict__ b3, const float* __restrict__ b4,
                     const float* __restrict__ b5,
                     const float* __restrict__ w6, const float* __restrict__ b6,
                     const _Float16* __restrict__ wt2,
                     float* __restrict__ out)
{
    // Zs[((v*8 + kc)*64 + lane)*8 + i] = Z[point n = lane&15, k = kc*32 + (lane>>4)*8 + i]
    __shared__ _Float16 Zs[CPLANE];   // 40960 B -> up to 4 blocks/CU
    float* redf = (float*)Zs;         // aliased reduction scratch (after last Z read)

    const int tid = threadIdx.x;
    const long gp0 = (long)blockIdx.x * PTS;

    // ---------------- layer 0: (3 -> 256), Taylor-mode, fp32 VALU ----------
    {
        const int p = tid & 15;
        const float x = xyt[(gp0 + p) * 3 + 0];
        const float y = xyt[(gp0 + p) * 3 + 1];
        const float t = xyt[(gp0 + p) * 3 + 2];
        #pragma unroll
        for (int half = 0; half < 2; ++half) {
            const int jg = (tid >> 4) + half * 16;   // 0..31, 8 features each
            f16x8 vh[5];
            #pragma unroll
            for (int cb = 0; cb < 2; ++cb) {         // two float4 groups of j
                const int jb = jg * 8 + cb * 4;
                const f32x4 wx4 = *(const f32x4*)&w0[0 * WIDTH + jb];
                const f32x4 wy4 = *(const f32x4*)&w0[1 * WIDTH + jb];
                const f32x4 wt4 = *(const f32x4*)&w0[2 * WIDTH + jb];
                const f32x4 bb4 = *(const f32x4*)&b0[jb];
                #pragma unroll
                for (int c = 0; c < 4; ++c) {
                    const float wx = wx4[c], wy = wy4[c], wt = wt4[c];
                    float zv, s;
                    tanh_s(fmaf(x, wx, fmaf(y, wy, fmaf(t, wt, bb4[c]))), zv, s);
                    const float vals[5] = { zv, s * wx, s * wy, s * wt,
                                            -2.0f * zv * s * (wx * wx + wy * wy) };
                    #pragma unroll
                    for (int v = 0; v < 5; ++v)
                        vh[v][cb * 4 + c] = (_Float16)vals[v];
                }
            }
            // j block jg*8..+7: kc = jg>>2, q' = jg&3, i = c
            #pragma unroll
            for (int v = 0; v < 5; ++v) {
                const int off = ((v * 8 + (jg >> 2)) * 64 + (jg & 3) * 16 + p) * 8;
                *(f16x8*)&Zs[off] = vh[v];
            }
        }
    }
    __syncthreads();

    // ------- hidden layers 1..5: MFMA fp16, single product per chain -------
    const float* Bsl[5] = { b1, b2, b3, b4, b5 };
    const int lane = tid & 63;
    const int wv   = tid >> 6;       // wave 0..3 -> M-tiles 4w..4w+3
    const int q    = lane >> 4;
    const int n15  = lane & 15;

    for (int l = 0; l < 5; ++l) {
        const _Float16* Wl = wt2 + l * 2 * 65536;
        f32x4 acc[5][4];
        #pragma unroll
        for (int v = 0; v < 5; ++v)
            #pragma unroll
            for (int Mt = 0; Mt < 4; ++Mt)
                acc[v][Mt] = (f32x4){0.f, 0.f, 0.f, 0.f};

        #pragma unroll 2
        for (int kc = 0; kc < 8; ++kc) {
            f16x8 Ah[4];
            #pragma unroll
            for (int Mt = 0; Mt < 4; ++Mt) {
                const int fo = (((wv * 4 + Mt) * 8 + kc) * 64 + lane) * 8;
                Ah[Mt] = *(const f16x8*)(Wl + fo);
            }
            #pragma unroll
            for (int v = 0; v < 5; ++v) {
                const int zo = ((v * 8 + kc) * 64 + lane) * 8;
                const f16x8 Bh = *(const f16x8*)&Zs[zo];
                #pragma unroll
                for (int Mt = 0; Mt < 4; ++Mt)
                    acc[v][Mt] = __builtin_amdgcn_mfma_f32_16x16x32_f16(
                                     Ah[Mt], Bh, acc[v][Mt], 0, 0, 0);
            }
        }
        __syncthreads();   // all Zs reads done before overwrite / redf alias

        const float* Bb = Bsl[l];
        if (l < 4) {
            // epilogue -> next-layer Z (fp16 hi); f32x4 vector math
            #pragma unroll
            for (int Mt = 0; Mt < 4; ++Mt) {
                const int jt = wv * 4 + Mt;
                const int j0 = jt * 16 + q * 4;
                const f32x4 bb = *(const f32x4*)&Bb[j0];
                f32x4 zv, sv;
                #pragma unroll
                for (int reg = 0; reg < 4; ++reg) {
                    float z_, s_;
                    tanh_s(acc[0][Mt][reg] + bb[reg], z_, s_);
                    zv[reg] = z_; sv[reg] = s_;
                }
                const f32x4 u1 = acc[1][Mt], u2 = acc[2][Mt];
                const f32x4 nv1 = sv * u1;
                const f32x4 nv2 = sv * u2;
                const f32x4 nv3 = sv * acc[3][Mt];
                const f32x4 m2zs = -2.0f * zv * sv;
                const f32x4 qq = u1 * u1 + u2 * u2;
                const f32x4 nv4 = sv * acc[4][Mt] + m2zs * qq;
                const f32x4 nvs[5] = { zv, nv1, nv2, nv3, nv4 };
                // j0 -> kc' = j0>>5, q'' = (j0>>3)&3, i0 = j0&7
                const int off0 = ((j0 >> 5) * 64 + ((j0 >> 3) & 3) * 16 + n15) * 8 + (j0 & 7);
                #pragma unroll
                for (int v = 0; v < 5; ++v) {
                    const h16x2 h01 = __builtin_amdgcn_cvt_pkrtz(nvs[v][0], nvs[v][1]);
                    const h16x2 h23 = __builtin_amdgcn_cvt_pkrtz(nvs[v][2], nvs[v][3]);
                    *(f16x4*)&Zs[v * 4096 + off0] =
                        (f16x4){ (_Float16)h01[0], (_Float16)h01[1],
                                 (_Float16)h23[0], (_Float16)h23[1] };
                }
            }
        } else {
            // final epilogue: tanh chain + fold w6 dot, f32x4 partials
            f32x4 pv[5];
            #pragma unroll
            for (int v = 0; v < 5; ++v) pv[v] = (f32x4){0.f, 0.f, 0.f, 0.f};
            #pragma unroll
            for (int Mt = 0; Mt < 4; ++Mt) {
                const int jt = wv * 4 + Mt;
                const int j0 = jt * 16 + q * 4;
                const f32x4 bb  = *(const f32x4*)&Bb[j0];
                const f32x4 w64 = *(const f32x4*)&w6[j0];
                f32x4 zv, sv;
                #pragma unroll
                for (int reg = 0; reg < 4; ++reg) {
                    float z_, s_;
                    tanh_s(acc[0][Mt][reg] + bb[reg], z_, s_);
                    zv[reg] = z_; sv[reg] = s_;
                }
                const f32x4 u1 = acc[1][Mt], u2 = acc[2][Mt];
                const f32x4 m2zs = -2.0f * zv * sv;
                const f32x4 qq = u1 * u1 + u2 * u2;
                pv[0] += zv * w64;
                pv[1] += (sv * u1) * w64;
                pv[2] += (sv * u2) * w64;
                pv[3] += (sv * acc[3][Mt]) * w64;
                pv[4] += (sv * acc[4][Mt] + m2zs * qq) * w64;
            }
            float part[5];
            #pragma unroll
            for (int v = 0; v < 5; ++v) {
                part[v] = (pv[v][0] + pv[v][1]) + (pv[v][2] + pv[v][3]);
                part[v] += __shfl_xor(part[v], 16, 64);
                part[v] += __shfl_xor(part[v], 32, 64);
            }
            // per-wave partials -> LDS (redf aliases Zs; all Zs reads barrier'd)
            if (q == 0) {
                #pragma unroll
                for (int v = 0; v < 5; ++v)
                    redf[wv * 80 + v * 16 + n15] = part[v];
            }
        }
        __syncthreads();
    }

    // ---------------- residual (sum 4 wave partials per chain) --------------
    if (tid < PTS) {
        const int p = tid;
        float tot[5];
        #pragma unroll
        for (int v = 0; v < 5; ++v)
            tot[v] = redf[0 * 80 + v * 16 + p] + redf[1 * 80 + v * 16 + p]
                   + redf[2 * 80 + v * 16 + p] + redf[3 * 80 + v * 16 + p];
        const float h   = tot[0] + b6[0];
        const float hx  = tot[1];
        const float hy  = tot[2];
        const float ht  = tot[3];
        const float lap = tot[4];
        const float x = xyt[(gp0 + p) * 3 + 0];
        const float y = xyt[(gp0 + p) * 3 + 1];
        const float t = xyt[(gp0 + p) * 3 + 2];
        const float pi = 3.14159265358979323846f;
        const float f = sinf(pi * x) * sinf(pi * y) * expf(-t);
        out[gp0 + p] = ht - 0.5f * (fmaf(h, lap, fmaf(hx, hx, hy * hy))) - f;
    }
}

extern "C" void kernel_launch(void* const* d_in, const int* in_sizes, int n_in,
                              void* d_out, int out_size, void* d_ws, size_t ws_size,
                              hipStream_t stream) {
    const float* xyt = (const float*)d_in[0];
    const float* w0  = (const float*)d_in[1];
    const float* b0  = (const float*)d_in[2];
    const float* w1  = (const float*)d_in[3];
    const float* b1  = (const float*)d_in[4];
    const float* w2  = (const float*)d_in[5];
    const float* b2  = (const float*)d_in[6];
    const float* w3  = (const float*)d_in[7];
    const float* b3  = (const float*)d_in[8];
    const float* w4  = (const float*)d_in[9];
    const float* b4  = (const float*)d_in[10];
    const float* w5  = (const float*)d_in[11];
    const float* b5  = (const float*)d_in[12];
    const float* w6  = (const float*)d_in[13];
    const float* b6  = (const float*)d_in[14];
    float* out = (float*)d_out;
    _Float16* wt2 = (_Float16*)d_ws;    // needs 5*2*65536*2 = 1,310,720 B

    prep_w_kernel<<<160, 256, 0, stream>>>(w1, w2, w3, w4, w5, wt2);

    const int npts = in_sizes[0] / 3;   // 131072
    dim3 grid(npts / PTS);              // 8192
    dim3 block(256);
    pde_mfma_kernel<<<grid, block, 0, stream>>>(xyt, w0, b0, b1, b2, b3, b4, b5,
                                                w6, b6, wt2, out);
}